// Round 6
// baseline (1346.199 us; speedup 1.0000x reference)
//
#include <hip/hip_runtime.h>

#define B_ 2
#define S_ 2048
#define D_ 2048
#define L_ 3
#define H_ 16
#define DH_ 128
#define BLK_ 16
#define NA_ 64
#define Q_ 1024
#define KV_ 3072
#define VOCAB_ 32000
#define MASK_ID_ 31999
#define NTOK_ (B_*Q_)          // 2048
#define VT2_ (VOCAB_/256)      // 125 col-tiles for LM head (256-wide)
#define NCHUNK_ 4

typedef __attribute__((ext_vector_type(8))) short bf16x8;
typedef __attribute__((ext_vector_type(4))) float f32x4;
typedef const __attribute__((address_space(1))) void* gptr_t;
typedef __attribute__((address_space(3))) void* lptr_t;

__device__ inline unsigned short f2bf(float x) {
  unsigned int u = __float_as_uint(x);
  unsigned int r = (u + 0x7fff + ((u >> 16) & 1)) >> 16;
  return (unsigned short)r;
}
__device__ inline float bf2f(unsigned short u) {
  return __uint_as_float(((unsigned int)u) << 16);
}

// ---------------- meta ----------------
__global__ void k_meta(const int* __restrict__ ids, const int* __restrict__ anchors,
                       int* __restrict__ dids, int* __restrict__ dpos, int* __restrict__ labels) {
  int t = blockIdx.x * 256 + threadIdx.x;
  if (t >= NTOK_) return;
  int b = t >> 10, qi = t & 1023;
  int a = qi >> 4, off = qi & 15;
  int ap = anchors[b * NA_ + a];
  dpos[t] = ap + off;
  dids[t] = (off == 0) ? ids[b * S_ + ap] : MASK_ID_;
  labels[t] = (off == 0) ? -100 : ids[b * S_ + ap + off];
}

// ---------------- f32 -> bf16 convert ----------------
__global__ void k_cvt(const float* __restrict__ in, unsigned short* __restrict__ out, int n4) {
  int i = blockIdx.x * 256 + threadIdx.x;
  if (i >= n4) return;
  float4 v = ((const float4*)in)[i];
  ushort4 o;
  o.x = f2bf(v.x); o.y = f2bf(v.y); o.z = f2bf(v.z); o.w = f2bf(v.w);
  ((ushort4*)out)[i] = o;
}

// ---------------- ctx_cat gather+convert ----------------
__global__ void k_cvt_ctx(const float* __restrict__ hs, unsigned short* __restrict__ out) {
  int bi = blockIdx.x;          // row*3 + l
  int l = bi % 3, row = bi / 3; // row = b*S+s
  const float4* src = (const float4*)(hs + ((size_t)l * B_ * S_ + row) * (size_t)D_);
  ushort4* dst = (ushort4*)(out + (size_t)row * (3 * D_) + (size_t)l * D_);
  for (int i = threadIdx.x; i < D_ / 4; i += 256) {
    float4 v = src[i];
    ushort4 o;
    o.x = f2bf(v.x); o.y = f2bf(v.y); o.z = f2bf(v.z); o.w = f2bf(v.w);
    dst[i] = o;
  }
}

// ---------------- embedding gather ----------------
__global__ void k_gather(const float* __restrict__ table, const int* __restrict__ dids,
                         unsigned short* __restrict__ x_kv) {
  int row = blockIdx.x;                 // 0..NTOK_
  int b = row >> 10, qi = row & 1023;
  const float4* src = (const float4*)(table + (size_t)dids[row] * D_);
  ushort4* dst = (ushort4*)(x_kv + ((size_t)b * KV_ + S_ + qi) * D_);
  for (int i = threadIdx.x; i < D_ / 4; i += 256) {
    float4 v = src[i];
    ushort4 o;
    o.x = f2bf(v.x); o.y = f2bf(v.y); o.z = f2bf(v.z); o.w = f2bf(v.w);
    dst[i] = o;
  }
}

// ================= ring-3 counted-vmcnt MFMA GEMM =================
// C[M,N] = A[M,K] @ Bw[N,K]^T.  BM=128, BN=256, BK=64, 8 waves (2M x 4N),
// 3-deep LDS ring (144 KiB), conflict-free XOR chunk swizzle, setprio MFMA.
// A row addressing: ra*K + (ra>>adivlog)*abump.
// CMODE 0: f32 store  CMODE 1: bf16 store (row addr +(row>>cdivlog)*cbump)
// CMODE 2: LM-head fused softmax/argmax partials per 256-col tile.
// Requires: M%128==0, N%256==0, K%64==0, K>=192, grid%8==0.
#define STAGE3(s_, kt_)                                                        \
  {                                                                            \
    unsigned short* as_ = &Asl[s_][0];                                         \
    unsigned short* bs_ = &Bsl[s_][0];                                         \
    _Pragma("unroll")                                                          \
    for (int i_ = 0; i_ < 2; ++i_)                                             \
      __builtin_amdgcn_global_load_lds((gptr_t)(A + aoff[i_] + (kt_)),         \
          (lptr_t)((char*)as_ + adst[i_]), 16, 0, 0);                          \
    _Pragma("unroll")                                                          \
    for (int i_ = 0; i_ < 4; ++i_)                                             \
      __builtin_amdgcn_global_load_lds((gptr_t)(Bw + boff[i_] + (kt_)),        \
          (lptr_t)((char*)bs_ + bdst[i_]), 16, 0, 0);                          \
  }

template <int CMODE>
__global__ __launch_bounds__(512, 1) void k_gemm3(
    const unsigned short* __restrict__ A, const unsigned short* __restrict__ Bw,
    float* __restrict__ Cf, unsigned short* __restrict__ Cb,
    int M, int N, int K, int adivlog, long long abump, int cdivlog, long long cbump,
    const int* __restrict__ labels, float* __restrict__ pm, float* __restrict__ ps,
    int* __restrict__ pbi, float* __restrict__ plab) {
  __shared__ unsigned short Asl[3][128 * 64];   // 48 KiB
  __shared__ unsigned short Bsl[3][256 * 64];   // 96 KiB
  int ntm = M >> 7;
  int per = gridDim.x >> 3;
  int wgid = (blockIdx.x & 7) * per + (blockIdx.x >> 3);  // XCD-chunked, bijective
  int by = wgid % ntm, bx = wgid / ntm;                   // row-fastest: B-panel L2 reuse
  int rowbase = by << 7, colbase = bx << 8;
  int tid = threadIdx.x, l = tid & 63, w = tid >> 6;
  int wm = w >> 2, wn = w & 3;
  int lo = l & 15, hi = l >> 4;

  // staging invariants: per-lane global offsets carry the inverse chunk swizzle
  long long aoff[2]; int adst[2];
#pragma unroll
  for (int i = 0; i < 2; ++i) {
    int rl = w * 16 + i * 8 + (l >> 3);
    int cu = (l & 7) ^ (rl & 7);
    long long ra = rowbase + rl;
    aoff[i] = ra * K + (ra >> adivlog) * abump + cu * 8;
    adst[i] = (w * 128 + i * 64) * 16;
  }
  long long boff[4]; int bdst[4];
#pragma unroll
  for (int i = 0; i < 4; ++i) {
    int rl = w * 32 + i * 8 + (l >> 3);
    int cu = (l & 7) ^ (rl & 7);
    long long rb = colbase + rl;
    boff[i] = rb * K + cu * 8;
    bdst[i] = (w * 256 + i * 64) * 16;
  }
  // fragment read offsets (ushort index), same swizzle on the read side
  int ard[4][2], brd[4][2];
#pragma unroll
  for (int m = 0; m < 4; ++m)
#pragma unroll
    for (int ks = 0; ks < 2; ++ks) {
      int row = wm * 64 + m * 16 + lo;
      int pos = ((ks << 2) | hi) ^ (row & 7);
      ard[m][ks] = row * 64 + pos * 8;
      row = wn * 64 + m * 16 + lo;
      pos = ((ks << 2) | hi) ^ (row & 7);
      brd[m][ks] = row * 64 + pos * 8;
    }

  f32x4 acc[4][4];
#pragma unroll
  for (int m = 0; m < 4; ++m)
#pragma unroll
    for (int n = 0; n < 4; ++n) acc[m][n] = (f32x4){0.f, 0.f, 0.f, 0.f};

  int NT = K >> 6;
  STAGE3(0, 0);
  STAGE3(1, 64);
  STAGE3(2, 128);

  int s = 0;
  for (int t = 0; t < NT; ++t) {
    // counted vmcnt: ensure tile t (oldest 6 loads) landed; tiles t+1,t+2 stay in flight
    if (t < NT - 2)       asm volatile("s_waitcnt vmcnt(12)" ::: "memory");
    else if (t == NT - 2) asm volatile("s_waitcnt vmcnt(6)" ::: "memory");
    else                  asm volatile("s_waitcnt vmcnt(0)" ::: "memory");
    __builtin_amdgcn_s_barrier();
    asm volatile("" ::: "memory");
    const unsigned short* as_ = &Asl[s][0];
    const unsigned short* bs_ = &Bsl[s][0];
    bf16x8 af[4][2], bg[4][2];
#pragma unroll
    for (int m = 0; m < 4; ++m)
#pragma unroll
      for (int ks = 0; ks < 2; ++ks) {
        af[m][ks] = *(const bf16x8*)(as_ + ard[m][ks]);
        bg[m][ks] = *(const bf16x8*)(bs_ + brd[m][ks]);
      }
    __builtin_amdgcn_s_setprio(1);
#pragma unroll
    for (int m = 0; m < 4; ++m)
#pragma unroll
      for (int n = 0; n < 4; ++n) {
        acc[m][n] = __builtin_amdgcn_mfma_f32_16x16x32_bf16(af[m][0], bg[n][0], acc[m][n], 0, 0, 0);
        acc[m][n] = __builtin_amdgcn_mfma_f32_16x16x32_bf16(af[m][1], bg[n][1], acc[m][n], 0, 0, 0);
      }
    __builtin_amdgcn_s_setprio(0);
    __builtin_amdgcn_sched_barrier(0);          // rule 18: pin MFMA before recycle barrier
    asm volatile("" ::: "memory");
    __builtin_amdgcn_s_barrier();               // all reads of slot s done
    if (t + 3 < NT) STAGE3(s, (t + 3) << 6);    // recycle slot s for tile t+3
    s = (s == 2) ? 0 : s + 1;
  }

  if (CMODE == 0 || CMODE == 1) {
#pragma unroll
    for (int m = 0; m < 4; ++m)
#pragma unroll
      for (int n = 0; n < 4; ++n)
#pragma unroll
        for (int r4 = 0; r4 < 4; ++r4) {
          int row = rowbase + wm * 64 + m * 16 + hi * 4 + r4;
          int col = colbase + wn * 64 + n * 16 + lo;
          size_t addr = (size_t)row * N + (size_t)(row >> cdivlog) * cbump + col;
          if (CMODE == 0) Cf[addr] = acc[m][n][r4];
          else Cb[addr] = f2bf(acc[m][n][r4]);
        }
  } else {
    // LM-head epilogue: 128 rows x 256 cols -> per-row max/argmax/sumexp/label
    float* f = (float*)&Asl[0][0];   // fmax[4][128] | fsum[4][128] | gmax[128] | flab[128]
    int* ii = (int*)&Bsl[0][0];      // iarg[4][128] | garg[128] | labs[128]
    if (tid < 128) { f[1152 + tid] = -3.0e38f; ii[640 + tid] = labels[rowbase + tid]; }
    __syncthreads();
#pragma unroll
    for (int m = 0; m < 4; ++m)
#pragma unroll
      for (int r4 = 0; r4 < 4; ++r4) {
        int rl = wm * 64 + m * 16 + hi * 4 + r4;
        float mx = acc[m][0][r4];
        int arg = colbase + wn * 64 + lo;
#pragma unroll
        for (int n = 1; n < 4; ++n) {
          float v = acc[m][n][r4];
          int c = colbase + wn * 64 + n * 16 + lo;
          if (v > mx) { mx = v; arg = c; }
        }
#pragma unroll
        for (int d = 1; d < 16; d <<= 1) {
          float om = __shfl_xor(mx, d);
          int oc = __shfl_xor(arg, d);
          if (om > mx || (om == mx && oc < arg)) { mx = om; arg = oc; }
        }
        if (lo == 0) { f[wn * 128 + rl] = mx; ii[wn * 128 + rl] = arg; }
      }
    __syncthreads();
    if (tid < 128) {
      float m0 = f[tid]; int a0 = ii[tid];
#pragma unroll
      for (int x = 1; x < 4; ++x) {
        float v = f[x * 128 + tid]; int c = ii[x * 128 + tid];
        if (v > m0 || (v == m0 && c < a0)) { m0 = v; a0 = c; }
      }
      f[1024 + tid] = m0; ii[512 + tid] = a0;
    }
    __syncthreads();
#pragma unroll
    for (int m = 0; m < 4; ++m)
#pragma unroll
      for (int r4 = 0; r4 < 4; ++r4) {
        int rl = wm * 64 + m * 16 + hi * 4 + r4;
        float gm = f[1024 + rl];
        float sacc = 0.f;
#pragma unroll
        for (int n = 0; n < 4; ++n) sacc += __expf(acc[m][n][r4] - gm);
#pragma unroll
        for (int d = 1; d < 16; d <<= 1) sacc += __shfl_xor(sacc, d);
        if (lo == 0) f[512 + wn * 128 + rl] = sacc;
        int lab = ii[640 + rl];
        int rel = lab - colbase;
        if (rel >= 0 && rel < 256 && (rel >> 6) == wn && (rel & 15) == lo) {
          int n_own = (rel >> 4) & 3;
#pragma unroll
          for (int n = 0; n < 4; ++n)
            if (n == n_own) f[1152 + rl] = acc[m][n][r4];
        }
      }
    __syncthreads();
    if (tid < 128) {
      int grow = rowbase + tid;
      size_t p = (size_t)grow * VT2_ + bx;
      pm[p] = f[1024 + tid];
      ps[p] = f[512 + tid] + f[512 + 128 + tid] + f[512 + 256 + tid] + f[512 + 384 + tid];
      pbi[p] = ii[512 + tid];
      plab[p] = f[1152 + tid];
    }
  }
}

// ---------------- old m97 kernel, kept only for the V^T scatter store ----------------
template <int CMODE, int MAP>
__global__ __launch_bounds__(256) void k_mfma_bt(
    const unsigned short* __restrict__ A, const unsigned short* __restrict__ Bw,
    float* __restrict__ Cf, unsigned short* __restrict__ Cb,
    int M, int N, int K, int adivlog, long long abump, int cdivlog, long long cbump) {
  __shared__ unsigned short As[128 * 32];
  __shared__ unsigned short Bs[128 * 32];
  int ntn = N >> 7;
  int bx = blockIdx.x % ntn, by = blockIdx.x / ntn;
  int rowbase = by << 7, colbase = bx << 7;
  int tid = threadIdx.x, lane = tid & 63, w = tid >> 6;
  int wr = w >> 1, wc = w & 1;
  int lo = lane & 15, hi = lane >> 4;

  f32x4 acc[4][4];
#pragma unroll
  for (int m = 0; m < 4; ++m)
#pragma unroll
    for (int n = 0; n < 4; ++n) acc[m][n] = (f32x4){0.f, 0.f, 0.f, 0.f};

  for (int kt = 0; kt < K; kt += 32) {
#pragma unroll
    for (int i = 0; i < 2; ++i) {
      int seg = i * 4 + w;
      int rloc = seg * 16 + (lane >> 2);
      int kcol = kt + ((lane & 3) << 3);
      int ra = rowbase + rloc;
      long long aoff = (long long)ra * K + (long long)(ra >> adivlog) * abump + kcol;
      __builtin_amdgcn_global_load_lds((gptr_t)(A + aoff), (lptr_t)(As + seg * 512), 16, 0, 0);
      int rb = colbase + rloc;
      long long boff = (long long)rb * K + kcol;
      __builtin_amdgcn_global_load_lds((gptr_t)(Bw + boff), (lptr_t)(Bs + seg * 512), 16, 0, 0);
    }
    __syncthreads();
    bf16x8 af[4], bfv[4];
#pragma unroll
    for (int m = 0; m < 4; ++m) {
      int row = wr * 64 + m * 16 + lo;
      af[m] = *(const bf16x8*)(As + row * 32 + (hi << 3));
    }
#pragma unroll
    for (int n = 0; n < 4; ++n) {
      int row = wc * 64 + n * 16 + lo;
      bfv[n] = *(const bf16x8*)(Bs + row * 32 + (hi << 3));
    }
#pragma unroll
    for (int m = 0; m < 4; ++m)
#pragma unroll
      for (int n = 0; n < 4; ++n)
        acc[m][n] = __builtin_amdgcn_mfma_f32_16x16x32_bf16(af[m], bfv[n], acc[m][n], 0, 0, 0);
    __syncthreads();
  }
  // CMODE 3: V^T store vt[b][h][dim][kv]
#pragma unroll
  for (int m = 0; m < 4; ++m)
#pragma unroll
    for (int n = 0; n < 4; ++n)
#pragma unroll
      for (int r4 = 0; r4 < 4; ++r4) {
        int row = rowbase + wr * 64 + m * 16 + hi * 4 + r4;
        int col = colbase + wc * 64 + n * 16 + lo;
        int bb = row >= KV_;
        int kv = row - bb * KV_;
        size_t addr = ((size_t)(bb * H_ + (col >> 7)) * 128 + (col & 127)) * KV_ + kv;
        Cb[addr] = f2bf(acc[m][n][r4]);
      }
}

// ---------------- RoPE in-place on bf16 ----------------
__global__ void k_rope(unsigned short* __restrict__ x, const int* __restrict__ dpos, int mode) {
  int idx = blockIdx.x * 256 + threadIdx.x;
  int j = idx & 63;
  int h = (idx >> 6) & 15;
  int row = idx >> 10;
  int pos;
  if (mode == 0) {
    if (row >= NTOK_) return;
    pos = dpos[row];
  } else {
    if (row >= B_ * KV_) return;
    int b = row / KV_, kvi = row % KV_;
    pos = (kvi < S_) ? kvi : dpos[b * Q_ + (kvi - S_)];
  }
  float inv = expf(-(float)j * (9.210340371976184f / 64.f));
  float ang = (float)pos * inv;
  float c = cosf(ang), s = sinf(ang);
  unsigned short* p = x + (size_t)row * D_ + h * DH_ + j;
  float x1 = bf2f(p[0]), x2 = bf2f(p[64]);
  p[0] = f2bf(x1 * c - x2 * s);
  p[64] = f2bf(x2 * c + x1 * s);
}

// ---------------- MFMA flash attention, 4-way context split ----------------
__global__ __launch_bounds__(256) void k_attn_part(
    const unsigned short* __restrict__ qb, const unsigned short* __restrict__ kb,
    const unsigned short* __restrict__ vt, const int* __restrict__ anchors,
    float* __restrict__ pm_att, float* __restrict__ pl_att, float* __restrict__ po_att) {
  __shared__ __align__(16) unsigned short P_all[4][16 * 40];
  int w = threadIdx.x >> 6, lane = threadIdx.x & 63;
  int blk = blockIdx.x * 4 + w;            // (((b*NA + a)*H + h)*4 + chunk)
  int chunk = blk & 3, h = (blk >> 2) & 15, a = (blk >> 6) & 63, b = blk >> 12;
  int ql = lane & 15, p = lane >> 4;
  int apos = anchors[b * NA_ + a];

  int cstart = chunk << 9;
  int cend = min(apos, cstart + 512);
  int len = (cend > cstart) ? (cend - cstart) : 0;
  int ntile = (len + 31) >> 5;
  int total = ntile + ((chunk == 3) ? 1 : 0);

  if (total == 0) {
    if (p == 0) { pm_att[blk * 16 + ql] = -3.0e38f; pl_att[blk * 16 + ql] = 0.f; }
    return;
  }
  unsigned short* P = P_all[w];

  const unsigned short* qbase = qb + ((size_t)(b * Q_ + a * 16 + ql)) * D_ + h * DH_;
  bf16x8 qf[4];
#pragma unroll
  for (int ks = 0; ks < 4; ++ks)
    qf[ks] = *(const bf16x8*)(qbase + ks * 32 + p * 8);

  const unsigned short* kbb = kb + (size_t)b * KV_ * D_ + h * DH_;
  const unsigned short* vtb = vt + ((size_t)(b * H_ + h)) * 128 * KV_;

  f32x4 o[8];
#pragma unroll
  for (int nt = 0; nt < 8; ++nt) o[nt] = (f32x4){0.f, 0.f, 0.f, 0.f};
  float mrun = -3.0e38f, lrun = 0.f;
  const float scl = 0.08838834764831845f;

  for (int t = 0; t < total; ++t) {
    bool isdraft = (chunk == 3) && (t == ntile);
    int ktb = isdraft ? (S_ + a * 16) : (cstart + (t << 5));
    int vc = isdraft ? 16 : min(32, cend - ktb);
    float s[2][4];
#pragma unroll
    for (int g = 0; g < 2; ++g) {
      if (g * 16 < vc) {
        f32x4 accs = (f32x4){0.f, 0.f, 0.f, 0.f};
        const unsigned short* krow = kbb + (size_t)(ktb + g * 16 + ql) * D_;
#pragma unroll
        for (int ks = 0; ks < 4; ++ks) {
          bf16x8 kf = *(const bf16x8*)(krow + ks * 32 + p * 8);
          accs = __builtin_amdgcn_mfma_f32_16x16x32_bf16(kf, qf[ks], accs, 0, 0, 0);
        }
#pragma unroll
        for (int r = 0; r < 4; ++r) {
          int kl = g * 16 + p * 4 + r;
          s[g][r] = (kl < vc) ? accs[r] * scl : -3.0e38f;
        }
      } else {
#pragma unroll
        for (int r = 0; r < 4; ++r) s[g][r] = -3.0e38f;
      }
    }
    float mt = s[0][0];
#pragma unroll
    for (int g = 0; g < 2; ++g)
#pragma unroll
      for (int r = 0; r < 4; ++r) mt = fmaxf(mt, s[g][r]);
    mt = fmaxf(mt, __shfl_xor(mt, 16));
    mt = fmaxf(mt, __shfl_xor(mt, 32));
    float mnew = fmaxf(mrun, mt);
    float corr = __expf(mrun - mnew);
    float psum = 0.f;
#pragma unroll
    for (int g = 0; g < 2; ++g) {
      float p0 = __expf(s[g][0] - mnew), p1 = __expf(s[g][1] - mnew);
      float p2 = __expf(s[g][2] - mnew), p3 = __expf(s[g][3] - mnew);
      psum += p0 + p1 + p2 + p3;
      ushort2 w0, w1;
      w0.x = f2bf(p0); w0.y = f2bf(p1); w1.x = f2bf(p2); w1.y = f2bf(p3);
      int eo = ql * 40 + g * 16 + p * 4;
      *(ushort2*)(P + eo) = w0;
      *(ushort2*)(P + eo + 2) = w1;
    }
    psum += __shfl_xor(psum, 16);
    psum += __shfl_xor(psum, 32);
    lrun = lrun * corr + psum;
    mrun = mnew;
    float cr[4];
#pragma unroll
    for (int r = 0; r < 4; ++r) cr[r] = __shfl(corr, p * 4 + r);
#pragma unroll
    for (int nt = 0; nt < 8; ++nt)
#pragma unroll
      for (int r = 0; r < 4; ++r) o[nt][r] *= cr[r];
    bf16x8 pf = *(const bf16x8*)(P + ql * 40 + p * 8);
#pragma unroll
    for (int nt = 0; nt < 8; ++nt) {
      bf16x8 vf = *(const bf16x8*)(vtb + (size_t)(nt * 16 + ql) * KV_ + ktb + p * 8);
      o[nt] = __builtin_amdgcn_mfma_f32_16x16x32_bf16(pf, vf, o[nt], 0, 0, 0);
    }
  }
  if (p == 0) { pm_att[blk * 16 + ql] = mrun; pl_att[blk * 16 + ql] = lrun; }
  float* pob = po_att + (size_t)blk * 2048;
#pragma unroll
  for (int nt = 0; nt < 8; ++nt)
#pragma unroll
    for (int r = 0; r < 4; ++r)
      pob[(p * 4 + r) * 128 + nt * 16 + ql] = o[nt][r];
}

// ---------------- combine attention partials ----------------
__global__ __launch_bounds__(256) void k_attn_combine(
    const float* __restrict__ pm_att, const float* __restrict__ pl_att,
    const float* __restrict__ po_att, unsigned short* __restrict__ ob) {
  int base = blockIdx.x;            // (b*NA+a)*H + h
  int h = base & 15, a = (base >> 4) & 63, b = base >> 10;
  int d = threadIdx.x & 127, qh = threadIdx.x >> 7;
  int pbase = base * 4;
#pragma unroll
  for (int qq = 0; qq < 8; ++qq) {
    int q = qh * 8 + qq;
    float m0 = pm_att[(pbase + 0) * 16 + q], m1 = pm_att[(pbase + 1) * 16 + q];
    float m2 = pm_att[(pbase + 2) * 16 + q], m3 = pm_att[(pbase + 3) * 16 + q];
    float mg = fmaxf(fmaxf(m0, m1), fmaxf(m2, m3));
    float w0 = __expf(m0 - mg), w1 = __expf(m1 - mg);
    float w2 = __expf(m2 - mg), w3 = __expf(m3 - mg);
    float lg = pl_att[(pbase + 0) * 16 + q] * w0 + pl_att[(pbase + 1) * 16 + q] * w1 +
               pl_att[(pbase + 2) * 16 + q] * w2 + pl_att[(pbase + 3) * 16 + q] * w3;
    float od = po_att[(size_t)(pbase + 0) * 2048 + q * 128 + d] * w0 +
               po_att[(size_t)(pbase + 1) * 2048 + q * 128 + d] * w1 +
               po_att[(size_t)(pbase + 2) * 2048 + q * 128 + d] * w2 +
               po_att[(size_t)(pbase + 3) * 2048 + q * 128 + d] * w3;
    ob[((size_t)(b * Q_ + a * 16 + q)) * D_ + h * DH_ + d] = f2bf(od / lg);
  }
}

// ---------------- residual + RMSNorm ----------------
__global__ void k_rmsnorm(const unsigned short* __restrict__ x_kv, const float* __restrict__ proj,
                          const float* __restrict__ nw, unsigned short* __restrict__ outp) {
  int row = blockIdx.x;
  int b = row >> 10, qi = row & 1023;
  const unsigned short* emb = x_kv + ((size_t)b * KV_ + S_ + qi) * D_;
  const float* pr = proj + (size_t)row * D_;
  __shared__ float red[256];
  float h[8];
  float ssum = 0.f;
#pragma unroll
  for (int i = 0; i < 8; ++i) {
    int d = threadIdx.x + i * 256;
    h[i] = bf2f(emb[d]) + pr[d];
    ssum += h[i] * h[i];
  }
  red[threadIdx.x] = ssum;
  __syncthreads();
  for (int s = 128; s; s >>= 1) {
    if (threadIdx.x < s) red[threadIdx.x] += red[threadIdx.x + s];
    __syncthreads();
  }
  float scale = rsqrtf(red[0] / (float)D_ + 1e-6f);
#pragma unroll
  for (int i = 0; i < 8; ++i) {
    int d = threadIdx.x + i * 256;
    outp[(size_t)row * D_ + d] = f2bf(h[i] * scale * nw[d]);
  }
}

// ---------------- combine LM-head partials ----------------
__global__ void k_combine(const float* __restrict__ pm, const float* __restrict__ ps,
                          const int* __restrict__ pbi, const float* __restrict__ plab,
                          const int* __restrict__ labels, float* __restrict__ ts) {
  int t = blockIdx.x * 256 + threadIdx.x;
  if (t >= NTOK_) return;
  const float* pmr = pm + (size_t)t * VT2_;
  const float* psr = ps + (size_t)t * VT2_;
  const int* pbir = pbi + (size_t)t * VT2_;
  const float* plabr = plab + (size_t)t * VT2_;
  float M = -3.0e38f; int bi = 0;
  for (int x = 0; x < VT2_; ++x) {
    float v = pmr[x];
    if (v > M) { M = v; bi = pbir[x]; }
  }
  float ssum = 0.f, labl = -3.0e38f;
  for (int x = 0; x < VT2_; ++x) {
    ssum += psr[x] * __expf(pmr[x] - M);
    labl = fmaxf(labl, plabr[x]);
  }
  float lse = M + logf(ssum);
  int lab = labels[t];
  int off = t & 15;
  float valid = (lab != -100) ? 1.f : 0.f;
  float w = (off == 0) ? 0.f : __expf(-(float)(off - 1) / 7.0f);
  w *= valid;
  float nll = (lab != -100) ? (lse - labl) : 0.f;
  float correct = (valid > 0.f && bi == lab) ? 1.f : 0.f;
  ts[t * 4 + 0] = nll * w;
  ts[t * 4 + 1] = w;
  ts[t * 4 + 2] = correct;
  ts[t * 4 + 3] = valid;
}

// ---------------- final reduction ----------------
__global__ void k_finalize(const float* __restrict__ ts, float* __restrict__ out) {
  __shared__ float r0[256], r1[256], r2[256], r3[256];
  int tid = threadIdx.x;
  float s0 = 0, s1 = 0, s2 = 0, s3 = 0;
  for (int t = tid; t < NTOK_; t += 256) {
    s0 += ts[t * 4 + 0]; s1 += ts[t * 4 + 1];
    s2 += ts[t * 4 + 2]; s3 += ts[t * 4 + 3];
  }
  r0[tid] = s0; r1[tid] = s1; r2[tid] = s2; r3[tid] = s3;
  __syncthreads();
  for (int s = 128; s; s >>= 1) {
    if (tid < s) {
      r0[tid] += r0[tid + s]; r1[tid] += r1[tid + s];
      r2[tid] += r2[tid + s]; r3[tid] += r3[tid + s];
    }
    __syncthreads();
  }
  if (tid == 0) {
    out[0] = r0[0] / fmaxf(r1[0], 1e-6f);
    out[1] = r2[0] / fmaxf(r3[0], 1.f);
  }
}

extern "C" void kernel_launch(void* const* d_in, const int* in_sizes, int n_in,
                              void* d_out, int out_size, void* d_ws, size_t ws_size,
                              hipStream_t stream) {
  const int* input_ids = (const int*)d_in[0];
  const float* hs = (const float*)d_in[1];
  const float* lm_head = (const float*)d_in[3];
  const float* norm_w = (const float*)d_in[4];
  const int* anchors = (const int*)d_in[5];
  const float* ctx_w = (const float*)d_in[6];
  const float* embed = (const float*)d_in[7];
  const float* wq = (const float*)d_in[8];
  const float* wk = (const float*)d_in[9];
  const float* wv = (const float*)d_in[10];
  const float* wo = (const float*)d_in[11];
  float* out = (float*)d_out;

  char* base = (char*)d_ws;
  size_t off = 0;
  unsigned short* x_kv_bf = (unsigned short*)(base + off); off += (size_t)B_ * KV_ * D_ * 2;
  unsigned short* wkb = (unsigned short*)(base + off); off += (size_t)D_ * D_ * 2;
  unsigned short* wvb = (unsigned short*)(base + off); off += (size_t)D_ * D_ * 2;
  unsigned short* wqb = (unsigned short*)(base + off); off += (size_t)D_ * D_ * 2;
  unsigned short* wob = (unsigned short*)(base + off); off += (size_t)D_ * D_ * 2;
  unsigned short* hidden_bf = (unsigned short*)(base + off); off += (size_t)NTOK_ * D_ * 2;
  unsigned short* attn_bf = (unsigned short*)(base + off); off += (size_t)NTOK_ * D_ * 2;
  float* proj = (float*)(base + off); off += (size_t)NTOK_ * D_ * 4;
  float* pm = (float*)(base + off); off += (size_t)NTOK_ * 250 * 4;
  float* psum = (float*)(base + off); off += (size_t)NTOK_ * 250 * 4;
  float* plab = (float*)(base + off); off += (size_t)NTOK_ * 250 * 4;
  int* pbi = (int*)(base + off); off += (size_t)NTOK_ * 250 * 4;
  float* tstats = (float*)(base + off); off += (size_t)NTOK_ * 4 * 4;
  int* dids = (int*)(base + off); off += NTOK_ * 4;
  int* dpos = (int*)(base + off); off += NTOK_ * 4;
  int* labels = (int*)(base + off); off += NTOK_ * 4;
  // REGION A (aliased): [ctxA | ctx_wbf | kbuf | vtbuf | qbuf], later reused as lm_bf.
  char* regA = base + off;
  const size_t SLACK = 65536;
  unsigned short* ctxA = (unsigned short*)(regA);                                   // 50.3 MB
  unsigned short* ctx_wbf = (unsigned short*)(regA + 50331648);                     // 25.2 MB
  unsigned short* kbuf = (unsigned short*)(regA + 50331648 + 25165824);
  unsigned short* vtbuf = (unsigned short*)(regA + 50331648 + 2 * 25165824 + SLACK);
  unsigned short* qbuf = (unsigned short*)(regA + 50331648 + 3 * 25165824 + 2 * SLACK);
  unsigned short* lm_bf = (unsigned short*)(regA);                                  // 131 MB alias
  float* po_att = (float*)(regA);                                                   // 67.1 MB (dead ctxA area)
  float* pm_att = (float*)(regA + 67108864);
  float* pl_att = (float*)(regA + 67108864 + 524288);

  k_meta<<<(NTOK_ + 255) / 256, 256, 0, stream>>>(input_ids, anchors, dids, dpos, labels);
  k_cvt<<<((D_ * (L_ * D_) / 4) + 255) / 256, 256, 0, stream>>>(ctx_w, ctx_wbf, D_ * (L_ * D_) / 4);
  k_cvt<<<((D_ * D_ / 4) + 255) / 256, 256, 0, stream>>>(wk, wkb, D_ * D_ / 4);
  k_cvt<<<((D_ * D_ / 4) + 255) / 256, 256, 0, stream>>>(wv, wvb, D_ * D_ / 4);
  k_cvt<<<((D_ * D_ / 4) + 255) / 256, 256, 0, stream>>>(wq, wqb, D_ * D_ / 4);
  k_cvt<<<((D_ * D_ / 4) + 255) / 256, 256, 0, stream>>>(wo, wob, D_ * D_ / 4);
  k_cvt_ctx<<<B_ * S_ * L_, 256, 0, stream>>>(hs, ctxA);
  k_gather<<<NTOK_, 256, 0, stream>>>(embed, dids, x_kv_bf);

  // ctx projection -> x_kv ctx rows (M=4096, N=2048, K=6144), grid 32*8=256
  k_gemm3<1><<<(4096 / 128) * (2048 / 256), 512, 0, stream>>>(
      ctxA, ctx_wbf, nullptr, x_kv_bf, 4096, 2048, 6144, 30, 0LL, 11, (long long)Q_ * D_,
      nullptr, nullptr, nullptr, nullptr, nullptr);
  // K (M=6144, N=2048, K=2048), grid 48*8=384
  k_gemm3<1><<<(6144 / 128) * (2048 / 256), 512, 0, stream>>>(
      x_kv_bf, wkb, nullptr, kbuf, 6144, 2048, 2048, 30, 0LL, 30, 0LL,
      nullptr, nullptr, nullptr, nullptr, nullptr);
  // V -> transposed store vt[b][h][dim][kv] (old kernel, scatter epilogue)
  k_mfma_bt<3, 0><<<(6144 / 128) * (2048 / 128), 256, 0, stream>>>(
      x_kv_bf, wvb, nullptr, vtbuf, 6144, 2048, 2048, 30, 0LL, 30, 0LL);
  // Q (M=2048), grid 16*8=128
  k_gemm3<1><<<(2048 / 128) * (2048 / 256), 512, 0, stream>>>(
      x_kv_bf + (size_t)S_ * D_, wqb, nullptr, qbuf, 2048, 2048, 2048, 10,
      (long long)(KV_ - Q_) * D_, 30, 0LL,
      nullptr, nullptr, nullptr, nullptr, nullptr);
  // RoPE
  k_rope<<<(NTOK_ * H_ * 64) / 256, 256, 0, stream>>>(qbuf, dpos, 0);
  k_rope<<<(B_ * KV_ * H_ * 64) / 256, 256, 0, stream>>>(kbuf, dpos, 1);
  // attention: 4-way context split + combine
  k_attn_part<<<(B_ * NA_ * H_ * NCHUNK_) / 4, 256, 0, stream>>>(
      qbuf, kbuf, vtbuf, anchors, pm_att, pl_att, po_att);
  k_attn_combine<<<B_ * NA_ * H_, 256, 0, stream>>>(pm_att, pl_att, po_att, attn_bf);
  // output projection -> f32
  k_gemm3<0><<<(2048 / 128) * (2048 / 256), 512, 0, stream>>>(
      attn_bf, wob, proj, nullptr, 2048, 2048, 2048, 30, 0LL, 30, 0LL,
      nullptr, nullptr, nullptr, nullptr, nullptr);
  // residual + RMSNorm
  k_rmsnorm<<<NTOK_, 256, 0, stream>>>(x_kv_bf, proj, norm_w, hidden_bf);
  // LM head convert (aliases REGION A — attention partials dead now)
  k_cvt<<<((VOCAB_ * D_ / 4) + 255) / 256, 256, 0, stream>>>(lm_head, lm_bf, VOCAB_ * D_ / 4);
  // LM head GEMM + fused partials (M=2048, N=32000, K=2048), grid 16*125=2000
  k_gemm3<2><<<(2048 / 128) * (VOCAB_ / 256), 512, 0, stream>>>(
      hidden_bf, lm_bf, nullptr, nullptr, 2048, VOCAB_, 2048, 30, 0LL, 30, 0LL,
      labels, pm, psum, pbi, plab);
  k_combine<<<(NTOK_ + 255) / 256, 256, 0, stream>>>(pm, psum, pbi, plab, labels, tstats);
  k_finalize<<<1, 256, 0, stream>>>(tstats, out);
}

// Round 8
// 1205.277 us; speedup vs baseline: 1.1169x; 1.1169x over previous
//
#include <hip/hip_runtime.h>

#define B_ 2
#define S_ 2048
#define D_ 2048
#define L_ 3
#define H_ 16
#define DH_ 128
#define BLK_ 16
#define NA_ 64
#define Q_ 1024
#define KV_ 3072
#define VOCAB_ 32000
#define MASK_ID_ 31999
#define NTOK_ (B_*Q_)          // 2048
#define VT2_ (VOCAB_/256)      // 125 col-tiles for LM head (256-wide)
#define NCHUNK_ 4

typedef __attribute__((ext_vector_type(8))) short bf16x8;
typedef __attribute__((ext_vector_type(4))) float f32x4;
typedef const __attribute__((address_space(1))) void* gptr_t;
typedef __attribute__((address_space(3))) void* lptr_t;

__device__ inline unsigned short f2bf(float x) {
  unsigned int u = __float_as_uint(x);
  unsigned int r = (u + 0x7fff + ((u >> 16) & 1)) >> 16;
  return (unsigned short)r;
}
__device__ inline float bf2f(unsigned short u) {
  return __uint_as_float(((unsigned int)u) << 16);
}

// ---------------- meta ----------------
__global__ void k_meta(const int* __restrict__ ids, const int* __restrict__ anchors,
                       int* __restrict__ dids, int* __restrict__ dpos, int* __restrict__ labels) {
  int t = blockIdx.x * 256 + threadIdx.x;
  if (t >= NTOK_) return;
  int b = t >> 10, qi = t & 1023;
  int a = qi >> 4, off = qi & 15;
  int ap = anchors[b * NA_ + a];
  dpos[t] = ap + off;
  dids[t] = (off == 0) ? ids[b * S_ + ap] : MASK_ID_;
  labels[t] = (off == 0) ? -100 : ids[b * S_ + ap + off];
}

// ---------------- f32 -> bf16 convert ----------------
__global__ void k_cvt(const float* __restrict__ in, unsigned short* __restrict__ out, int n4) {
  int i = blockIdx.x * 256 + threadIdx.x;
  if (i >= n4) return;
  float4 v = ((const float4*)in)[i];
  ushort4 o;
  o.x = f2bf(v.x); o.y = f2bf(v.y); o.z = f2bf(v.z); o.w = f2bf(v.w);
  ((ushort4*)out)[i] = o;
}

// ---------------- ctx_cat gather+convert ----------------
__global__ void k_cvt_ctx(const float* __restrict__ hs, unsigned short* __restrict__ out) {
  int bi = blockIdx.x;          // row*3 + l
  int l = bi % 3, row = bi / 3; // row = b*S+s
  const float4* src = (const float4*)(hs + ((size_t)l * B_ * S_ + row) * (size_t)D_);
  ushort4* dst = (ushort4*)(out + (size_t)row * (3 * D_) + (size_t)l * D_);
  for (int i = threadIdx.x; i < D_ / 4; i += 256) {
    float4 v = src[i];
    ushort4 o;
    o.x = f2bf(v.x); o.y = f2bf(v.y); o.z = f2bf(v.z); o.w = f2bf(v.w);
    dst[i] = o;
  }
}

// ---------------- embedding gather ----------------
__global__ void k_gather(const float* __restrict__ table, const int* __restrict__ dids,
                         unsigned short* __restrict__ x_kv) {
  int row = blockIdx.x;                 // 0..NTOK_
  int b = row >> 10, qi = row & 1023;
  const float4* src = (const float4*)(table + (size_t)dids[row] * D_);
  ushort4* dst = (ushort4*)(x_kv + ((size_t)b * KV_ + S_ + qi) * D_);
  for (int i = threadIdx.x; i < D_ / 4; i += 256) {
    float4 v = src[i];
    ushort4 o;
    o.x = f2bf(v.x); o.y = f2bf(v.y); o.z = f2bf(v.z); o.w = f2bf(v.w);
    dst[i] = o;
  }
}

// ================= 256x256 BK=64 counted-vmcnt double-buffer GEMM (LM head) ======
// C[M,N] = A[M,K] @ Bw[N,K]^T, fused softmax/argmax partials per 256-col tile.
// 512 threads = 8 waves (2M x 4N), per-wave 128x64 output, acc[8][4].
// LDS 128 KiB: 2 bufs x (256x64 A + 256x64 B).
// STAGING (fixed per m104 rule #21): LDS dest is WAVE-UNIFORM byte base
// (rowblock*128, char arithmetic), lane l lands at +l*16 = row (l>>3), chunk
// (l&7); per-lane GLOBAL source carries inverse XOR swizzle cu=(l&7)^(row&7).
// Read side applies the same XOR (involution verified in r6, absmax 0).
// Schedule per K-tile: STAGE(next) -> vmcnt(8) -> barrier -> 64 MFMA -> barrier.
#define STAGE2(buf_, kt_)                                                      \
  {                                                                            \
    _Pragma("unroll")                                                          \
    for (int i_ = 0; i_ < 4; ++i_) {                                           \
      __builtin_amdgcn_global_load_lds((gptr_t)(A + aoff[i_] + (kt_)),         \
          (lptr_t)((char*)Asl2 + (buf_) * 32768 + abase[i_]), 16, 0, 0);       \
      __builtin_amdgcn_global_load_lds((gptr_t)(Bw + boff[i_] + (kt_)),        \
          (lptr_t)((char*)Bsl2 + (buf_) * 32768 + bbase[i_]), 16, 0, 0);       \
    }                                                                          \
  }

__global__ __launch_bounds__(512, 1) void k_gemm2(
    const unsigned short* __restrict__ A, const unsigned short* __restrict__ Bw,
    int M, int N, int K,
    const int* __restrict__ labels, float* __restrict__ pm, float* __restrict__ ps,
    int* __restrict__ pbi, float* __restrict__ plab) {
  __shared__ unsigned short Asl2[2 * 256 * 64];   // 64 KiB
  __shared__ unsigned short Bsl2[2 * 256 * 64];   // 64 KiB
  int ntm = M >> 8;                               // 8
  int per = gridDim.x >> 3;
  int wgid = (blockIdx.x & 7) * per + (blockIdx.x >> 3);  // XCD-chunked, bijective
  int by = wgid % ntm, bx = wgid / ntm;                   // row-fastest: B-panel reuse
  int rowbase = by << 8, colbase = bx << 8;
  int tid = threadIdx.x, l = tid & 63, w = tid >> 6;
  int wm = w >> 2, wn = w & 3;
  int lo = l & 15, hi = l >> 4;

  // staging: (wave w, round i) covers 8 rows starting at (w*4+i)*8.
  // lane l -> row rb8+(l>>3), LDS chunk (l&7); source chunk cu=(l&7)^(row&7).
  long long aoff[4], boff[4];
  int abase[4], bbase[4];
#pragma unroll
  for (int i = 0; i < 4; ++i) {
    int rb8 = (w * 4 + i) * 8;          // wave-uniform row-block start
    int r = rb8 + (l >> 3);
    int cu = (l & 7) ^ (r & 7);
    aoff[i] = (long long)(rowbase + r) * K + cu * 8;
    boff[i] = (long long)(colbase + r) * K + cu * 8;
    abase[i] = rb8 * 128;               // BYTES, uniform per wave (row = 128 B)
    bbase[i] = rb8 * 128;
  }
  // frag read offsets (ushort units), same XOR on the read side
  int ard[8][2], brd[4][2];
#pragma unroll
  for (int m = 0; m < 8; ++m)
#pragma unroll
    for (int ks = 0; ks < 2; ++ks) {
      int r = wm * 128 + m * 16 + lo;
      int p = ((ks << 2) | hi) ^ (r & 7);
      ard[m][ks] = r * 64 + p * 8;
    }
#pragma unroll
  for (int n = 0; n < 4; ++n)
#pragma unroll
    for (int ks = 0; ks < 2; ++ks) {
      int r = wn * 64 + n * 16 + lo;
      int p = ((ks << 2) | hi) ^ (r & 7);
      brd[n][ks] = r * 64 + p * 8;
    }

  f32x4 acc[8][4];
#pragma unroll
  for (int m = 0; m < 8; ++m)
#pragma unroll
    for (int n = 0; n < 4; ++n) acc[m][n] = (f32x4){0.f, 0.f, 0.f, 0.f};

  int NT = K >> 6;
  int cur = 0;
  STAGE2(0, 0);
  for (int t = 0; t < NT; ++t) {
    if (t + 1 < NT) {
      STAGE2(cur ^ 1, (t + 1) << 6);
      asm volatile("s_waitcnt vmcnt(8)" ::: "memory");   // tile t landed; t+1 in flight
    } else {
      asm volatile("s_waitcnt vmcnt(0)" ::: "memory");
    }
    __builtin_amdgcn_s_barrier();
    asm volatile("" ::: "memory");
    const unsigned short* as_ = Asl2 + cur * 16384;
    const unsigned short* bs_ = Bsl2 + cur * 16384;
    __builtin_amdgcn_s_setprio(1);
#pragma unroll
    for (int ks = 0; ks < 2; ++ks) {
      bf16x8 af[8], bg[4];
#pragma unroll
      for (int m = 0; m < 8; ++m) af[m] = *(const bf16x8*)(as_ + ard[m][ks]);
#pragma unroll
      for (int n = 0; n < 4; ++n) bg[n] = *(const bf16x8*)(bs_ + brd[n][ks]);
#pragma unroll
      for (int m = 0; m < 8; ++m)
#pragma unroll
        for (int n = 0; n < 4; ++n)
          acc[m][n] = __builtin_amdgcn_mfma_f32_16x16x32_bf16(af[m], bg[n], acc[m][n], 0, 0, 0);
    }
    __builtin_amdgcn_s_setprio(0);
    __builtin_amdgcn_sched_barrier(0);
    asm volatile("" ::: "memory");
    __builtin_amdgcn_s_barrier();     // reads of buf[cur] done -> next iter may restage it
    cur ^= 1;
  }

  // ---- epilogue: 256 rows x 256 cols -> per-row max/argmax/sumexp/label ----
  float* f = (float*)Asl2;  // fmax[4][256] | fsum[4][256] @1024 | gmax @2048 | flab @2304
  int* ii = (int*)Bsl2;     // iarg[4][256] | garg @1024 | labs @1280
  __syncthreads();
  if (tid < 256) { f[2304 + tid] = -3.0e38f; ii[1280 + tid] = labels[rowbase + tid]; }
  __syncthreads();
#pragma unroll
  for (int m = 0; m < 8; ++m)
#pragma unroll
    for (int r4 = 0; r4 < 4; ++r4) {
      int rl = wm * 128 + m * 16 + hi * 4 + r4;
      float mx = acc[m][0][r4];
      int arg = colbase + wn * 64 + lo;
#pragma unroll
      for (int n = 1; n < 4; ++n) {
        float v = acc[m][n][r4];
        int c = colbase + wn * 64 + n * 16 + lo;
        if (v > mx) { mx = v; arg = c; }
      }
#pragma unroll
      for (int d = 1; d < 16; d <<= 1) {
        float om = __shfl_xor(mx, d);
        int oc = __shfl_xor(arg, d);
        if (om > mx || (om == mx && oc < arg)) { mx = om; arg = oc; }
      }
      if (lo == 0) { f[wn * 256 + rl] = mx; ii[wn * 256 + rl] = arg; }
    }
  __syncthreads();
  if (tid < 256) {
    float m0 = f[tid]; int a0 = ii[tid];
#pragma unroll
    for (int x = 1; x < 4; ++x) {
      float v = f[x * 256 + tid]; int c = ii[x * 256 + tid];
      if (v > m0 || (v == m0 && c < a0)) { m0 = v; a0 = c; }
    }
    f[2048 + tid] = m0; ii[1024 + tid] = a0;
  }
  __syncthreads();
#pragma unroll
  for (int m = 0; m < 8; ++m)
#pragma unroll
    for (int r4 = 0; r4 < 4; ++r4) {
      int rl = wm * 128 + m * 16 + hi * 4 + r4;
      float gm = f[2048 + rl];
      float sacc = 0.f;
#pragma unroll
      for (int n = 0; n < 4; ++n) sacc += __expf(acc[m][n][r4] - gm);
#pragma unroll
      for (int d = 1; d < 16; d <<= 1) sacc += __shfl_xor(sacc, d);
      if (lo == 0) f[1024 + wn * 256 + rl] = sacc;
      int lab = ii[1280 + rl];
      int rel = lab - colbase;
      if (rel >= 0 && rel < 256 && (rel >> 6) == wn && (rel & 15) == lo) {
        int n_own = (rel >> 4) & 3;
#pragma unroll
        for (int n = 0; n < 4; ++n)
          if (n == n_own) f[2304 + rl] = acc[m][n][r4];
      }
    }
  __syncthreads();
  if (tid < 256) {
    int grow = rowbase + tid;
    size_t p = (size_t)grow * VT2_ + bx;
    pm[p] = f[2048 + tid];
    ps[p] = f[1024 + tid] + f[1024 + 256 + tid] + f[1024 + 512 + tid] + f[1024 + 768 + tid];
    pbi[p] = ii[1024 + tid];
    plab[p] = f[2304 + tid];
  }
}

// ---------------- m97 128x128 MFMA GEMM (measured-good; ctx/K/V/Q/O) ----------------
// CMODE 0: f32 store   CMODE 1: bf16 store   CMODE 3: bf16 V^T scatter store
template <int CMODE>
__global__ __launch_bounds__(256) void k_mfma_bt(
    const unsigned short* __restrict__ A, const unsigned short* __restrict__ Bw,
    float* __restrict__ Cf, unsigned short* __restrict__ Cb,
    int M, int N, int K, int adivlog, long long abump, int cdivlog, long long cbump) {
  __shared__ unsigned short As[128 * 32];
  __shared__ unsigned short Bs[128 * 32];
  int ntn = N >> 7;
  int bx = blockIdx.x % ntn, by = blockIdx.x / ntn;
  int rowbase = by << 7, colbase = bx << 7;
  int tid = threadIdx.x, lane = tid & 63, w = tid >> 6;
  int wr = w >> 1, wc = w & 1;
  int lo = lane & 15, hi = lane >> 4;

  f32x4 acc[4][4];
#pragma unroll
  for (int m = 0; m < 4; ++m)
#pragma unroll
    for (int n = 0; n < 4; ++n) acc[m][n] = (f32x4){0.f, 0.f, 0.f, 0.f};

  for (int kt = 0; kt < K; kt += 32) {
#pragma unroll
    for (int i = 0; i < 2; ++i) {
      int seg = i * 4 + w;
      int rloc = seg * 16 + (lane >> 2);
      int kcol = kt + ((lane & 3) << 3);
      int ra = rowbase + rloc;
      long long aoff = (long long)ra * K + (long long)(ra >> adivlog) * abump + kcol;
      __builtin_amdgcn_global_load_lds((gptr_t)(A + aoff), (lptr_t)(As + seg * 512), 16, 0, 0);
      int rb = colbase + rloc;
      long long boff = (long long)rb * K + kcol;
      __builtin_amdgcn_global_load_lds((gptr_t)(Bw + boff), (lptr_t)(Bs + seg * 512), 16, 0, 0);
    }
    __syncthreads();
    bf16x8 af[4], bfv[4];
#pragma unroll
    for (int m = 0; m < 4; ++m) {
      int row = wr * 64 + m * 16 + lo;
      af[m] = *(const bf16x8*)(As + row * 32 + (hi << 3));
    }
#pragma unroll
    for (int n = 0; n < 4; ++n) {
      int row = wc * 64 + n * 16 + lo;
      bfv[n] = *(const bf16x8*)(Bs + row * 32 + (hi << 3));
    }
#pragma unroll
    for (int m = 0; m < 4; ++m)
#pragma unroll
      for (int n = 0; n < 4; ++n)
        acc[m][n] = __builtin_amdgcn_mfma_f32_16x16x32_bf16(af[m], bfv[n], acc[m][n], 0, 0, 0);
    __syncthreads();
  }

  if (CMODE == 0 || CMODE == 1) {
#pragma unroll
    for (int m = 0; m < 4; ++m)
#pragma unroll
      for (int n = 0; n < 4; ++n)
#pragma unroll
        for (int r4 = 0; r4 < 4; ++r4) {
          int row = rowbase + wr * 64 + m * 16 + hi * 4 + r4;
          int col = colbase + wc * 64 + n * 16 + lo;
          size_t addr = (size_t)row * N + (size_t)(row >> cdivlog) * cbump + col;
          if (CMODE == 0) Cf[addr] = acc[m][n][r4];
          else Cb[addr] = f2bf(acc[m][n][r4]);
        }
  } else {
    // V^T store: row = b*KV + kv, col = h*128 + dim -> vt[b][h][dim][kv]
#pragma unroll
    for (int m = 0; m < 4; ++m)
#pragma unroll
      for (int n = 0; n < 4; ++n)
#pragma unroll
        for (int r4 = 0; r4 < 4; ++r4) {
          int row = rowbase + wr * 64 + m * 16 + hi * 4 + r4;
          int col = colbase + wc * 64 + n * 16 + lo;
          int bb = row >= KV_;
          int kv = row - bb * KV_;
          size_t addr = ((size_t)(bb * H_ + (col >> 7)) * 128 + (col & 127)) * KV_ + kv;
          Cb[addr] = f2bf(acc[m][n][r4]);
        }
  }
}

// ---------------- RoPE in-place on bf16 ----------------
__global__ void k_rope(unsigned short* __restrict__ x, const int* __restrict__ dpos, int mode) {
  int idx = blockIdx.x * 256 + threadIdx.x;
  int j = idx & 63;
  int h = (idx >> 6) & 15;
  int row = idx >> 10;
  int pos;
  if (mode == 0) {
    if (row >= NTOK_) return;
    pos = dpos[row];
  } else {
    if (row >= B_ * KV_) return;
    int b = row / KV_, kvi = row % KV_;
    pos = (kvi < S_) ? kvi : dpos[b * Q_ + (kvi - S_)];
  }
  float inv = expf(-(float)j * (9.210340371976184f / 64.f));
  float ang = (float)pos * inv;
  float c = cosf(ang), s = sinf(ang);
  unsigned short* p = x + (size_t)row * D_ + h * DH_ + j;
  float x1 = bf2f(p[0]), x2 = bf2f(p[64]);
  p[0] = f2bf(x1 * c - x2 * s);
  p[64] = f2bf(x2 * c + x1 * s);
}

// ---------------- MFMA flash attention, 4-way context split ----------------
__global__ __launch_bounds__(256) void k_attn_part(
    const unsigned short* __restrict__ qb, const unsigned short* __restrict__ kb,
    const unsigned short* __restrict__ vt, const int* __restrict__ anchors,
    float* __restrict__ pm_att, float* __restrict__ pl_att, float* __restrict__ po_att) {
  __shared__ __align__(16) unsigned short P_all[4][16 * 40];
  int w = threadIdx.x >> 6, lane = threadIdx.x & 63;
  int blk = blockIdx.x * 4 + w;            // (((b*NA + a)*H + h)*4 + chunk)
  int chunk = blk & 3, h = (blk >> 2) & 15, a = (blk >> 6) & 63, b = blk >> 12;
  int ql = lane & 15, p = lane >> 4;
  int apos = anchors[b * NA_ + a];

  int cstart = chunk << 9;
  int cend = min(apos, cstart + 512);
  int len = (cend > cstart) ? (cend - cstart) : 0;
  int ntile = (len + 31) >> 5;
  int total = ntile + ((chunk == 3) ? 1 : 0);

  if (total == 0) {
    if (p == 0) { pm_att[blk * 16 + ql] = -3.0e38f; pl_att[blk * 16 + ql] = 0.f; }
    return;
  }
  unsigned short* P = P_all[w];

  const unsigned short* qbase = qb + ((size_t)(b * Q_ + a * 16 + ql)) * D_ + h * DH_;
  bf16x8 qf[4];
#pragma unroll
  for (int ks = 0; ks < 4; ++ks)
    qf[ks] = *(const bf16x8*)(qbase + ks * 32 + p * 8);

  const unsigned short* kbb = kb + (size_t)b * KV_ * D_ + h * DH_;
  const unsigned short* vtb = vt + ((size_t)(b * H_ + h)) * 128 * KV_;

  f32x4 o[8];
#pragma unroll
  for (int nt = 0; nt < 8; ++nt) o[nt] = (f32x4){0.f, 0.f, 0.f, 0.f};
  float mrun = -3.0e38f, lrun = 0.f;
  const float scl = 0.08838834764831845f;

  for (int t = 0; t < total; ++t) {
    bool isdraft = (chunk == 3) && (t == ntile);
    int ktb = isdraft ? (S_ + a * 16) : (cstart + (t << 5));
    int vc = isdraft ? 16 : min(32, cend - ktb);
    float s[2][4];
#pragma unroll
    for (int g = 0; g < 2; ++g) {
      if (g * 16 < vc) {
        f32x4 accs = (f32x4){0.f, 0.f, 0.f, 0.f};
        const unsigned short* krow = kbb + (size_t)(ktb + g * 16 + ql) * D_;
#pragma unroll
        for (int ks = 0; ks < 4; ++ks) {
          bf16x8 kf = *(const bf16x8*)(krow + ks * 32 + p * 8);
          accs = __builtin_amdgcn_mfma_f32_16x16x32_bf16(kf, qf[ks], accs, 0, 0, 0);
        }
#pragma unroll
        for (int r = 0; r < 4; ++r) {
          int kl = g * 16 + p * 4 + r;
          s[g][r] = (kl < vc) ? accs[r] * scl : -3.0e38f;
        }
      } else {
#pragma unroll
        for (int r = 0; r < 4; ++r) s[g][r] = -3.0e38f;
      }
    }
    float mt = s[0][0];
#pragma unroll
    for (int g = 0; g < 2; ++g)
#pragma unroll
      for (int r = 0; r < 4; ++r) mt = fmaxf(mt, s[g][r]);
    mt = fmaxf(mt, __shfl_xor(mt, 16));
    mt = fmaxf(mt, __shfl_xor(mt, 32));
    float mnew = fmaxf(mrun, mt);
    float corr = __expf(mrun - mnew);
    float psum = 0.f;
#pragma unroll
    for (int g = 0; g < 2; ++g) {
      float p0 = __expf(s[g][0] - mnew), p1 = __expf(s[g][1] - mnew);
      float p2 = __expf(s[g][2] - mnew), p3 = __expf(s[g][3] - mnew);
      psum += p0 + p1 + p2 + p3;
      ushort2 w0, w1;
      w0.x = f2bf(p0); w0.y = f2bf(p1); w1.x = f2bf(p2); w1.y = f2bf(p3);
      int eo = ql * 40 + g * 16 + p * 4;
      *(ushort2*)(P + eo) = w0;
      *(ushort2*)(P + eo + 2) = w1;
    }
    psum += __shfl_xor(psum, 16);
    psum += __shfl_xor(psum, 32);
    lrun = lrun * corr + psum;
    mrun = mnew;
    float cr[4];
#pragma unroll
    for (int r = 0; r < 4; ++r) cr[r] = __shfl(corr, p * 4 + r);
#pragma unroll
    for (int nt = 0; nt < 8; ++nt)
#pragma unroll
      for (int r = 0; r < 4; ++r) o[nt][r] *= cr[r];
    bf16x8 pf = *(const bf16x8*)(P + ql * 40 + p * 8);
#pragma unroll
    for (int nt = 0; nt < 8; ++nt) {
      bf16x8 vf = *(const bf16x8*)(vtb + (size_t)(nt * 16 + ql) * KV_ + ktb + p * 8);
      o[nt] = __builtin_amdgcn_mfma_f32_16x16x32_bf16(pf, vf, o[nt], 0, 0, 0);
    }
  }
  if (p == 0) { pm_att[blk * 16 + ql] = mrun; pl_att[blk * 16 + ql] = lrun; }
  float* pob = po_att + (size_t)blk * 2048;
#pragma unroll
  for (int nt = 0; nt < 8; ++nt)
#pragma unroll
    for (int r = 0; r < 4; ++r)
      pob[(p * 4 + r) * 128 + nt * 16 + ql] = o[nt][r];
}

// ---------------- combine attention partials ----------------
__global__ __launch_bounds__(256) void k_attn_combine(
    const float* __restrict__ pm_att, const float* __restrict__ pl_att,
    const float* __restrict__ po_att, unsigned short* __restrict__ ob) {
  int base = blockIdx.x;            // (b*NA+a)*H + h
  int h = base & 15, a = (base >> 4) & 63, b = base >> 10;
  int d = threadIdx.x & 127, qh = threadIdx.x >> 7;
  int pbase = base * 4;
#pragma unroll
  for (int qq = 0; qq < 8; ++qq) {
    int q = qh * 8 + qq;
    float m0 = pm_att[(pbase + 0) * 16 + q], m1 = pm_att[(pbase + 1) * 16 + q];
    float m2 = pm_att[(pbase + 2) * 16 + q], m3 = pm_att[(pbase + 3) * 16 + q];
    float mg = fmaxf(fmaxf(m0, m1), fmaxf(m2, m3));
    float w0 = __expf(m0 - mg), w1 = __expf(m1 - mg);
    float w2 = __expf(m2 - mg), w3 = __expf(m3 - mg);
    float lg = pl_att[(pbase + 0) * 16 + q] * w0 + pl_att[(pbase + 1) * 16 + q] * w1 +
               pl_att[(pbase + 2) * 16 + q] * w2 + pl_att[(pbase + 3) * 16 + q] * w3;
    float od = po_att[(size_t)(pbase + 0) * 2048 + q * 128 + d] * w0 +
               po_att[(size_t)(pbase + 1) * 2048 + q * 128 + d] * w1 +
               po_att[(size_t)(pbase + 2) * 2048 + q * 128 + d] * w2 +
               po_att[(size_t)(pbase + 3) * 2048 + q * 128 + d] * w3;
    ob[((size_t)(b * Q_ + a * 16 + q)) * D_ + h * DH_ + d] = f2bf(od / lg);
  }
}

// ---------------- residual + RMSNorm ----------------
__global__ void k_rmsnorm(const unsigned short* __restrict__ x_kv, const float* __restrict__ proj,
                          const float* __restrict__ nw, unsigned short* __restrict__ outp) {
  int row = blockIdx.x;
  int b = row >> 10, qi = row & 1023;
  const unsigned short* emb = x_kv + ((size_t)b * KV_ + S_ + qi) * D_;
  const float* pr = proj + (size_t)row * D_;
  __shared__ float red[256];
  float h[8];
  float ssum = 0.f;
#pragma unroll
  for (int i = 0; i < 8; ++i) {
    int d = threadIdx.x + i * 256;
    h[i] = bf2f(emb[d]) + pr[d];
    ssum += h[i] * h[i];
  }
  red[threadIdx.x] = ssum;
  __syncthreads();
  for (int s = 128; s; s >>= 1) {
    if (threadIdx.x < s) red[threadIdx.x] += red[threadIdx.x + s];
    __syncthreads();
  }
  float scale = rsqrtf(red[0] / (float)D_ + 1e-6f);
#pragma unroll
  for (int i = 0; i < 8; ++i) {
    int d = threadIdx.x + i * 256;
    outp[(size_t)row * D_ + d] = f2bf(h[i] * scale * nw[d]);
  }
}

// ---------------- combine LM-head partials ----------------
__global__ void k_combine(const float* __restrict__ pm, const float* __restrict__ ps,
                          const int* __restrict__ pbi, const float* __restrict__ plab,
                          const int* __restrict__ labels, float* __restrict__ ts) {
  int t = blockIdx.x * 256 + threadIdx.x;
  if (t >= NTOK_) return;
  const float* pmr = pm + (size_t)t * VT2_;
  const float* psr = ps + (size_t)t * VT2_;
  const int* pbir = pbi + (size_t)t * VT2_;
  const float* plabr = plab + (size_t)t * VT2_;
  float M = -3.0e38f; int bi = 0;
  for (int x = 0; x < VT2_; ++x) {
    float v = pmr[x];
    if (v > M) { M = v; bi = pbir[x]; }
  }
  float ssum = 0.f, labl = -3.0e38f;
  for (int x = 0; x < VT2_; ++x) {
    ssum += psr[x] * __expf(pmr[x] - M);
    labl = fmaxf(labl, plabr[x]);
  }
  float lse = M + logf(ssum);
  int lab = labels[t];
  int off = t & 15;
  float valid = (lab != -100) ? 1.f : 0.f;
  float w = (off == 0) ? 0.f : __expf(-(float)(off - 1) / 7.0f);
  w *= valid;
  float nll = (lab != -100) ? (lse - labl) : 0.f;
  float correct = (valid > 0.f && bi == lab) ? 1.f : 0.f;
  ts[t * 4 + 0] = nll * w;
  ts[t * 4 + 1] = w;
  ts[t * 4 + 2] = correct;
  ts[t * 4 + 3] = valid;
}

// ---------------- final reduction ----------------
__global__ void k_finalize(const float* __restrict__ ts, float* __restrict__ out) {
  __shared__ float r0[256], r1[256], r2[256], r3[256];
  int tid = threadIdx.x;
  float s0 = 0, s1 = 0, s2 = 0, s3 = 0;
  for (int t = tid; t < NTOK_; t += 256) {
    s0 += ts[t * 4 + 0]; s1 += ts[t * 4 + 1];
    s2 += ts[t * 4 + 2]; s3 += ts[t * 4 + 3];
  }
  r0[tid] = s0; r1[tid] = s1; r2[tid] = s2; r3[tid] = s3;
  __syncthreads();
  for (int s = 128; s; s >>= 1) {
    if (tid < s) {
      r0[tid] += r0[tid + s]; r1[tid] += r1[tid + s];
      r2[tid] += r2[tid + s]; r3[tid] += r3[tid + s];
    }
    __syncthreads();
  }
  if (tid == 0) {
    out[0] = r0[0] / fmaxf(r1[0], 1e-6f);
    out[1] = r2[0] / fmaxf(r3[0], 1.f);
  }
}

extern "C" void kernel_launch(void* const* d_in, const int* in_sizes, int n_in,
                              void* d_out, int out_size, void* d_ws, size_t ws_size,
                              hipStream_t stream) {
  const int* input_ids = (const int*)d_in[0];
  const float* hs = (const float*)d_in[1];
  const float* lm_head = (const float*)d_in[3];
  const float* norm_w = (const float*)d_in[4];
  const int* anchors = (const int*)d_in[5];
  const float* ctx_w = (const float*)d_in[6];
  const float* embed = (const float*)d_in[7];
  const float* wq = (const float*)d_in[8];
  const float* wk = (const float*)d_in[9];
  const float* wv = (const float*)d_in[10];
  const float* wo = (const float*)d_in[11];
  float* out = (float*)d_out;

  char* base = (char*)d_ws;
  size_t off = 0;
  unsigned short* x_kv_bf = (unsigned short*)(base + off); off += (size_t)B_ * KV_ * D_ * 2;
  unsigned short* wkb = (unsigned short*)(base + off); off += (size_t)D_ * D_ * 2;
  unsigned short* wvb = (unsigned short*)(base + off); off += (size_t)D_ * D_ * 2;
  unsigned short* wqb = (unsigned short*)(base + off); off += (size_t)D_ * D_ * 2;
  unsigned short* wob = (unsigned short*)(base + off); off += (size_t)D_ * D_ * 2;
  unsigned short* hidden_bf = (unsigned short*)(base + off); off += (size_t)NTOK_ * D_ * 2;
  unsigned short* attn_bf = (unsigned short*)(base + off); off += (size_t)NTOK_ * D_ * 2;
  float* proj = (float*)(base + off); off += (size_t)NTOK_ * D_ * 4;
  float* pm = (float*)(base + off); off += (size_t)NTOK_ * VT2_ * 4;
  float* psum = (float*)(base + off); off += (size_t)NTOK_ * VT2_ * 4;
  float* plab = (float*)(base + off); off += (size_t)NTOK_ * VT2_ * 4;
  int* pbi = (int*)(base + off); off += (size_t)NTOK_ * VT2_ * 4;
  float* tstats = (float*)(base + off); off += (size_t)NTOK_ * 4 * 4;
  int* dids = (int*)(base + off); off += NTOK_ * 4;
  int* dpos = (int*)(base + off); off += NTOK_ * 4;
  int* labels = (int*)(base + off); off += NTOK_ * 4;
  // REGION A (aliased): [ctxA | ctx_wbf | kbuf | vtbuf | qbuf], later reused as lm_bf.
  char* regA = base + off;
  const size_t SLACK = 65536;
  unsigned short* ctxA = (unsigned short*)(regA);                                   // 50.3 MB
  unsigned short* ctx_wbf = (unsigned short*)(regA + 50331648);                     // 25.2 MB
  unsigned short* kbuf = (unsigned short*)(regA + 50331648 + 25165824);
  unsigned short* vtbuf = (unsigned short*)(regA + 50331648 + 2 * 25165824 + SLACK);
  unsigned short* qbuf = (unsigned short*)(regA + 50331648 + 3 * 25165824 + 2 * SLACK);
  unsigned short* lm_bf = (unsigned short*)(regA);                                  // 131 MB alias
  float* po_att = (float*)(regA);                                                   // 67.1 MB (dead ctxA area)
  float* pm_att = (float*)(regA + 67108864);
  float* pl_att = (float*)(regA + 67108864 + 524288);

  k_meta<<<(NTOK_ + 255) / 256, 256, 0, stream>>>(input_ids, anchors, dids, dpos, labels);
  k_cvt<<<((D_ * (L_ * D_) / 4) + 255) / 256, 256, 0, stream>>>(ctx_w, ctx_wbf, D_ * (L_ * D_) / 4);
  k_cvt<<<((D_ * D_ / 4) + 255) / 256, 256, 0, stream>>>(wk, wkb, D_ * D_ / 4);
  k_cvt<<<((D_ * D_ / 4) + 255) / 256, 256, 0, stream>>>(wv, wvb, D_ * D_ / 4);
  k_cvt<<<((D_ * D_ / 4) + 255) / 256, 256, 0, stream>>>(wq, wqb, D_ * D_ / 4);
  k_cvt<<<((D_ * D_ / 4) + 255) / 256, 256, 0, stream>>>(wo, wob, D_ * D_ / 4);
  k_cvt_ctx<<<B_ * S_ * L_, 256, 0, stream>>>(hs, ctxA);
  k_gather<<<NTOK_, 256, 0, stream>>>(embed, dids, x_kv_bf);

  // ctx projection -> x_kv ctx rows
  k_mfma_bt<1><<<(4096 / 128) * (2048 / 128), 256, 0, stream>>>(
      ctxA, ctx_wbf, nullptr, x_kv_bf, 4096, 2048, 6144, 30, 0LL, 11, (long long)Q_ * D_);
  // K
  k_mfma_bt<1><<<(6144 / 128) * (2048 / 128), 256, 0, stream>>>(
      x_kv_bf, wkb, nullptr, kbuf, 6144, 2048, 2048, 30, 0LL, 30, 0LL);
  // V -> transposed store vt[b][h][dim][kv]
  k_mfma_bt<3><<<(6144 / 128) * (2048 / 128), 256, 0, stream>>>(
      x_kv_bf, wvb, nullptr, vtbuf, 6144, 2048, 2048, 30, 0LL, 30, 0LL);
  // Q
  k_mfma_bt<1><<<(2048 / 128) * (2048 / 128), 256, 0, stream>>>(
      x_kv_bf + (size_t)S_ * D_, wqb, nullptr, qbuf, 2048, 2048, 2048, 10,
      (long long)(KV_ - Q_) * D_, 30, 0LL);
  // RoPE
  k_rope<<<(NTOK_ * H_ * 64) / 256, 256, 0, stream>>>(qbuf, dpos, 0);
  k_rope<<<(B_ * KV_ * H_ * 64) / 256, 256, 0, stream>>>(kbuf, dpos, 1);
  // attention: 4-way context split + combine
  k_attn_part<<<(B_ * NA_ * H_ * NCHUNK_) / 4, 256, 0, stream>>>(
      qbuf, kbuf, vtbuf, anchors, pm_att, pl_att, po_att);
  k_attn_combine<<<B_ * NA_ * H_, 256, 0, stream>>>(pm_att, pl_att, po_att, attn_bf);
  // output projection -> f32
  k_mfma_bt<0><<<(2048 / 128) * (2048 / 128), 256, 0, stream>>>(
      attn_bf, wob, proj, nullptr, 2048, 2048, 2048, 30, 0LL, 30, 0LL);
  // residual + RMSNorm
  k_rmsnorm<<<NTOK_, 256, 0, stream>>>(x_kv_bf, proj, norm_w, hidden_bf);
  // LM head convert (aliases REGION A — attention partials dead now)
  k_cvt<<<((VOCAB_ * D_ / 4) + 255) / 256, 256, 0, stream>>>(lm_head, lm_bf, VOCAB_ * D_ / 4);
  // LM head: 256x256 counted-vmcnt dbuf GEMM + fused partials (grid 8*125=1000)
  k_gemm2<<<(2048 / 256) * (VOCAB_ / 256), 512, 0, stream>>>(
      hidden_bf, lm_bf, 2048, VOCAB_, 2048, labels, pm, psum, pbi, plab);
  k_combine<<<(NTOK_ + 255) / 256, 256, 0, stream>>>(pm, psum, pbi, plab, labels, tstats);
  k_finalize<<<1, 256, 0, stream>>>(tstats, out);
}